// Round 7
// baseline (1038.762 us; speedup 1.0000x reference)
//
#include <hip/hip_runtime.h>
#include <cstdint>

// ---------------- problem constants ----------------
#define BQ 4
#define SEQ 1024
#define EMB 1024
#define NH 16
#define DKH 64
#define DFF 4096
#define MROWS 4096          // BQ*SEQ
#define NSAMP 35            // sample_k == n_top == 35
#define QKV_LD 3072

typedef int   i32x4 __attribute__((ext_vector_type(4)));
typedef float f32x4 __attribute__((ext_vector_type(4)));
typedef short s16x8 __attribute__((ext_vector_type(8)));
typedef __bf16 b16x8 __attribute__((ext_vector_type(8)));

// ---------- bf16 helpers ----------
__device__ __forceinline__ unsigned short bf16b(float f) {
  unsigned u = __builtin_bit_cast(unsigned, f);
  return (unsigned short)((u + 0x7FFFu + ((u >> 16) & 1u)) >> 16);
}

// ---------- MFMA wrapper: SFINAE over operand element type ----------
template <typename T> struct other_vec { using type = b16x8; };
template <> struct other_vec<b16x8>    { using type = s16x8; };

template <typename T>
__device__ __forceinline__ auto mfma_try(T a, T b, f32x4 c, int)
    -> decltype(__builtin_amdgcn_mfma_f32_16x16x32_bf16(a, b, c, 0, 0, 0)) {
  return __builtin_amdgcn_mfma_f32_16x16x32_bf16(a, b, c, 0, 0, 0);
}
template <typename T>
__device__ __forceinline__ f32x4 mfma_try(T a, T b, f32x4 c, long) {
  using U = typename other_vec<T>::type;
  U a2 = __builtin_bit_cast(U, a);
  U b2 = __builtin_bit_cast(U, b);
  return __builtin_amdgcn_mfma_f32_16x16x32_bf16(a2, b2, c, 0, 0, 0);
}
__device__ __forceinline__ f32x4 mfma_bf16(i32x4 a, i32x4 b, f32x4 c) {
  s16x8 as = __builtin_bit_cast(s16x8, a);
  s16x8 bs = __builtin_bit_cast(s16x8, b);
  return mfma_try(as, bs, c, 0);
}

// ---------- async global->LDS (16B per lane) ----------
typedef const __attribute__((address_space(1))) void GV;
typedef __attribute__((address_space(3))) void LV;
__device__ __forceinline__ void gload_lds16(const void* g, void* l) {
  __builtin_amdgcn_global_load_lds((GV*)(uintptr_t)g,
                                   (LV*)(unsigned)(uintptr_t)l, 16, 0, 0);
}

// ---------- Threefry-2x32 (20 rounds), JAX-compatible ----------
__device__ __forceinline__ void tf2x32(unsigned k0, unsigned k1, unsigned x0, unsigned x1,
                                       unsigned& o0, unsigned& o1) {
  unsigned ks2 = k0 ^ k1 ^ 0x1BD11BDAu;
  x0 += k0; x1 += k1;
#define TFR(r) { x0 += x1; x1 = (x1 << r) | (x1 >> (32 - r)); x1 ^= x0; }
  TFR(13) TFR(15) TFR(26) TFR(6)   x0 += k1;  x1 += ks2 + 1u;
  TFR(17) TFR(29) TFR(16) TFR(24)  x0 += ks2; x1 += k0 + 2u;
  TFR(13) TFR(15) TFR(26) TFR(6)   x0 += k0;  x1 += k1 + 3u;
  TFR(17) TFR(29) TFR(16) TFR(24)  x0 += k1;  x1 += ks2 + 4u;
  TFR(13) TFR(15) TFR(26) TFR(6)   x0 += ks2; x1 += k0 + 5u;
#undef TFR
  o0 = x0; o1 = x1;
}

__global__ void idx_kernel(int* __restrict__ out) {
  int t = blockIdx.x * 256 + threadIdx.x;       // 0..71679
  if (t >= 2 * SEQ * NSAMP) return;
  int sel = t >= SEQ * NSAMP;
  int i = sel ? t - SEQ * NSAMP : t;
  unsigned s0, s1, d0, d1;
  tf2x32(0u, 42u, 0u, 0u, s0, s1);              // k1
  tf2x32(0u, 42u, 0u, 1u, d0, d1);              // k2
  unsigned key0 = sel ? d0 : s0, key1 = sel ? d1 : s1;
  unsigned o0, o1;
  tf2x32(key0, key1, 0u, (unsigned)i, o0, o1);
  out[t] = (int)((o0 ^ o1) & 1023u);
}

// ---------- fp32 -> bf16 elementwise ----------
__global__ void f2b_kernel(const float* __restrict__ in, unsigned short* __restrict__ out, int n4) {
  int i = blockIdx.x * 256 + threadIdx.x;
  if (i >= n4) return;
  float4 v = ((const float4*)in)[i];
  uint2 p;
  p.x = (unsigned)bf16b(v.x) | ((unsigned)bf16b(v.y) << 16);
  p.y = (unsigned)bf16b(v.z) | ((unsigned)bf16b(v.w) << 16);
  ((uint2*)out)[i] = p;
}

// ---------- W (KxN f32) -> WT (NxK bf16) ----------
__global__ void transpose_kernel(const float* __restrict__ W, unsigned short* __restrict__ WT,
                                 int K, int N) {
  __shared__ float tile[32][33];
  int n0 = blockIdx.x * 32, k0 = blockIdx.y * 32;
  int tx = threadIdx.x, ty = threadIdx.y;       // 32 x 8
#pragma unroll
  for (int r = 0; r < 4; ++r)
    tile[ty * 4 + r][tx] = W[(size_t)(k0 + ty * 4 + r) * N + n0 + tx];
  __syncthreads();
#pragma unroll
  for (int r = 0; r < 4; ++r) {
    int n = n0 + ty * 4 + r, k = k0 + tx;
    WT[(size_t)n * K + k] = bf16b(tile[tx][ty * 4 + r]);
  }
}

__global__ void biascat_kernel(const float* q, const float* k, const float* v,
                               const float* ck, const float* cv,
                               float* qkvB, float* kvB) {
  int t = blockIdx.x * 256 + threadIdx.x;
  if (t < 1024) {
    qkvB[t] = q[t]; qkvB[1024 + t] = k[t]; qkvB[2048 + t] = v[t];
    kvB[t] = ck[t]; kvB[1024 + t] = cv[t];
  }
}

// ---------- bf16 MFMA GEMM, 128x128 tile, BK=32, 256 thr ----------
// EPI 0: C=acc+bias (f32, row-major ldc). EPI 1: Cb = bf16(gelu(acc+bias)).
// EPI 2: head-major QKV scatter: C[which][bh][l][d], which=(col+colofs)>>10.
template <int EPI>
__global__ __launch_bounds__(256) void gemm_kernel(
    const unsigned short* __restrict__ A, int lda,
    const unsigned short* __restrict__ BT, int ldb,
    float* __restrict__ C, int ldc,
    unsigned short* __restrict__ Cb, int ldcb,
    const float* __restrict__ bias, int K, int colofs) {
  __shared__ alignas(16) unsigned short As[128 * 32];
  __shared__ alignas(16) unsigned short Bs[128 * 32];
  const int tid = threadIdx.x;
  const int bm = blockIdx.y << 7, bn = blockIdx.x << 7;
  const int wave = tid >> 6, lane = tid & 63;
  const int wm = (wave & 1) << 6, wn = (wave >> 1) << 6;
  const int lr = lane & 15, lg = lane >> 4;

  f32x4 acc[4][4];
#pragma unroll
  for (int i = 0; i < 4; ++i)
#pragma unroll
    for (int j = 0; j < 4; ++j) acc[i][j] = f32x4{0.f, 0.f, 0.f, 0.f};

  const int trow = tid >> 2, tcol = (tid & 3) << 3;
  const unsigned short* Ag = A + (size_t)(bm + trow) * lda + tcol;
  const unsigned short* Bg = BT + (size_t)(bn + trow) * ldb + tcol;
  unsigned short* Al = &As[tid * 8];
  unsigned short* Bl = &Bs[tid * 8];

  for (int kt = 0; kt < K; kt += 32) {
    __syncthreads();
    gload_lds16(Ag + kt, Al);
    gload_lds16(Ag + (size_t)64 * lda + kt, Al + 2048);
    gload_lds16(Bg + kt, Bl);
    gload_lds16(Bg + (size_t)64 * ldb + kt, Bl + 2048);
    __syncthreads();
    i32x4 af[4], bf[4];
#pragma unroll
    for (int i = 0; i < 4; ++i)
      af[i] = *(const i32x4*)&As[(wm + i * 16 + lr) * 32 + lg * 8];
#pragma unroll
    for (int j = 0; j < 4; ++j)
      bf[j] = *(const i32x4*)&Bs[(wn + j * 16 + lr) * 32 + lg * 8];
#pragma unroll
    for (int i = 0; i < 4; ++i)
#pragma unroll
      for (int j = 0; j < 4; ++j)
        acc[i][j] = mfma_bf16(af[i], bf[j], acc[i][j]);
  }
#pragma unroll
  for (int i = 0; i < 4; ++i)
#pragma unroll
    for (int j = 0; j < 4; ++j)
#pragma unroll
      for (int r = 0; r < 4; ++r) {
        int row = bm + wm + i * 16 + lg * 4 + r;
        int col = bn + wn + j * 16 + lr;
        float v = acc[i][j][r] + bias[col];
        if constexpr (EPI == 0) {
          C[(size_t)row * ldc + col] = v;
        } else if constexpr (EPI == 1) {
          float gl = 0.5f * v * (1.f + erff(v * 0.70710678118654752f));
          Cb[(size_t)row * ldcb + col] = bf16b(gl);
        } else {
          int cc = col + colofs;
          int which = cc >> 10;
          int h = (cc >> 6) & 15;
          int d = col & 63;
          int b = row >> 10, l = row & 1023;
          C[((size_t)which << 22) + (((b << 4) + h) << 16) + (l << 6) + d] = v;
        }
      }
}

// ---------- 256x256 tile, BK=32, 512 thr, 2-phase prefetch (T3 minimum) ----------
template <int EPI>
__global__ __launch_bounds__(512, 2) void gemm256_kernel(
    const unsigned short* __restrict__ A, int lda,
    const unsigned short* __restrict__ BT, int ldb,
    float* __restrict__ C, int ldc,
    unsigned short* __restrict__ Cb, int ldcb,
    const float* __restrict__ bias, int K, int colofs) {
  __shared__ alignas(16) unsigned short As2[2][256 * 32];
  __shared__ alignas(16) unsigned short Bs2[2][256 * 32];
  const int tid = threadIdx.x;
  const int bm = blockIdx.y << 8, bn = blockIdx.x << 8;
  const int wave = tid >> 6, lane = tid & 63;
  const int wm2 = (wave >> 2) << 7;          // 0 or 128 (M)
  const int wn4 = (wave & 3) << 6;           // 0..192 (N)
  const int lr = lane & 15, lg = lane >> 4;

  f32x4 acc[8][4];
#pragma unroll
  for (int i = 0; i < 8; ++i)
#pragma unroll
    for (int j = 0; j < 4; ++j) acc[i][j] = f32x4{0.f, 0.f, 0.f, 0.f};

  const int srow = tid >> 2, scol = (tid & 3) << 3;
  auto STAGE = [&](int sb, int kt) {
#pragma unroll
    for (int p = 0; p < 2; ++p) {
      int rr = p * 128 + srow;
      gload_lds16(A + (size_t)(bm + rr) * lda + kt + scol,
                  &As2[sb][(size_t)(p * 512 + tid) * 8]);
      gload_lds16(BT + (size_t)(bn + rr) * ldb + kt + scol,
                  &Bs2[sb][(size_t)(p * 512 + tid) * 8]);
    }
  };

  STAGE(0, 0);
  __syncthreads();
  int buf = 0;
  for (int kt = 0; kt < K; kt += 32) {
    if (kt + 32 < K) STAGE(buf ^ 1, kt + 32);
    i32x4 af[8], bfr[4];
#pragma unroll
    for (int i = 0; i < 8; ++i)
      af[i] = *(const i32x4*)&As2[buf][(wm2 + i * 16 + lr) * 32 + lg * 8];
#pragma unroll
    for (int j = 0; j < 4; ++j)
      bfr[j] = *(const i32x4*)&Bs2[buf][(wn4 + j * 16 + lr) * 32 + lg * 8];
#pragma unroll
    for (int i = 0; i < 8; ++i)
#pragma unroll
      for (int j = 0; j < 4; ++j)
        acc[i][j] = mfma_bf16(af[i], bfr[j], acc[i][j]);
    __syncthreads();
    buf ^= 1;
  }
#pragma unroll
  for (int i = 0; i < 8; ++i)
#pragma unroll
    for (int j = 0; j < 4; ++j)
#pragma unroll
      for (int r = 0; r < 4; ++r) {
        int row = bm + wm2 + i * 16 + lg * 4 + r;
        int col = bn + wn4 + j * 16 + lr;
        float v = acc[i][j][r] + bias[col];
        if constexpr (EPI == 0) {
          C[(size_t)row * ldc + col] = v;
        } else if constexpr (EPI == 1) {
          float gl = 0.5f * v * (1.f + erff(v * 0.70710678118654752f));
          Cb[(size_t)row * ldcb + col] = bf16b(gl);
        } else {
          int cc = col + colofs;
          int which = cc >> 10;
          int h = (cc >> 6) & 15;
          int d = col & 63;
          int b = row >> 10, l = row & 1023;
          C[((size_t)which << 22) + (((b << 4) + h) << 16) + (l << 6) + d] = v;
        }
      }
}

// ---------- M = max_s(q.k_samp) - sum_s(q.k_samp)/1024, head-major ----------
// m5 structure (one query per wave) + XCD pinning (all blocks of a bh on one
// XCD -> K/Q panels L2-resident). 16384 blocks, 16384%8==0 so id&7 == XCD.
// Per-XCD working set: 8 bh x (256KB K + 256KB Q) = 4 MB ~= L2.
__global__ __launch_bounds__(256) void m6_kernel(
    const float* __restrict__ Qh, const float* __restrict__ Kh,
    const int* __restrict__ idx, float* __restrict__ Mout) {
  __shared__ float dots[4][36];
  const int id = blockIdx.x;
  const int xcd = id & 7, slot = id >> 3;            // slot 0..2047
  const int bh = xcd * 8 + (slot & 7);               // 8 bh per XCD
  const int qbase = (slot >> 3) << 2;                // 256 chunks x 4 queries
  const int tid = threadIdx.x, wv = tid >> 6, lane = tid & 63;
  const int l = qbase + wv;
  const float* Qr = Qh + ((size_t)bh << 16) + ((size_t)l << 6);
  if (lane < NSAMP) {
    const int s = idx[l * NSAMP + lane];
    const float* Kr = Kh + ((size_t)bh << 16) + ((size_t)s << 6);
    float pa[4] = {0.f, 0.f, 0.f, 0.f};
#pragma unroll
    for (int d4 = 0; d4 < 16; ++d4) {
      float4 k4 = *(const float4*)(Kr + d4 * 4);
      float4 q4 = *(const float4*)(Qr + d4 * 4);     // uniform -> broadcast
      pa[d4 & 3] = fmaf(k4.x, q4.x, pa[d4 & 3]);
      pa[d4 & 3] = fmaf(k4.y, q4.y, pa[d4 & 3]);
      pa[d4 & 3] = fmaf(k4.z, q4.z, pa[d4 & 3]);
      pa[d4 & 3] = fmaf(k4.w, q4.w, pa[d4 & 3]);
    }
    dots[wv][lane] = (pa[0] + pa[1]) + (pa[2] + pa[3]);
  }
  __syncthreads();
  if (tid < 16) {
    int q = tid >> 2, cp = tid & 3;
    int sb = cp * 9, se = (cp == 3) ? NSAMP : (sb + 9);
    float mx = -__builtin_inff(), sm = 0.f;
    for (int s = sb; s < se; ++s) {
      float v = dots[q][s];
      mx = fmaxf(mx, v);
      sm += v;
    }
    mx = fmaxf(mx, __shfl_xor(mx, 1, 64)); sm += __shfl_xor(sm, 1, 64);
    mx = fmaxf(mx, __shfl_xor(mx, 2, 64)); sm += __shfl_xor(sm, 2, 64);
    if (cp == 0) Mout[bh * 1024 + qbase + q] = mx - sm * (1.f / 1024.f);
  }
}

// ---------- single-wave top-35 per (b,h) ----------
__device__ __forceinline__ void amax2(float& v, int& id, float v2, int id2) {
  if (v2 > v || (v2 == v && id2 < id)) { v = v2; id = id2; }
}
__global__ __launch_bounds__(64) void topk2_kernel(
    const float* __restrict__ Mbuf, int* __restrict__ topOut) {
  const int bh = blockIdx.x, t = threadIdx.x;
  float v[16]; int li[16];
#pragma unroll
  for (int r = 0; r < 16; ++r) { int l = t + (r << 6); v[r] = Mbuf[bh * 1024 + l]; li[r] = l; }
  for (int it = 0; it < NSAMP; ++it) {
    float bv = v[0]; int bi = li[0];
#pragma unroll
    for (int r = 1; r < 16; ++r) amax2(bv, bi, v[r], li[r]);
#pragma unroll
    for (int m = 1; m < 64; m <<= 1) {
      float ov = __shfl_xor(bv, m, 64); int oi = __shfl_xor(bi, m, 64);
      amax2(bv, bi, ov, oi);
    }
    if (t == 0) topOut[bh * NSAMP + it] = bi;
#pragma unroll
    for (int r = 0; r < 16; ++r) if (li[r] == bi) v[r] = -__builtin_inff();
  }
}

// ---------- v sums per (b,h,d), head-major ----------
__global__ void vmean_kernel(const float* __restrict__ Vh, float* __restrict__ vmean) {
  const int g = blockIdx.x, bh = g >> 3, ch = g & 7;
  const int d = threadIdx.x;
  const float* Vb = Vh + ((size_t)bh << 16) + (ch * 128 << 6) + d;
  float s = 0.f;
  for (int l = 0; l < 128; ++l) s += Vb[l << 6];
  atomicAdd(&vmean[bh * 64 + d], s);
}

// ---------- fill O with broadcast v-mean (bf16) ----------
__global__ void fillO_kernel(const float* __restrict__ vmean, unsigned short* __restrict__ Ob) {
  int i = blockIdx.x * 256 + threadIdx.x;     // 4096*1024
  int e = i & 1023, b = i >> 20;
  int h = e >> 6, d = e & 63;
  Ob[i] = bf16b(vmean[((b << 4) + h) * 64 + d] * (1.f / 1024.f));
}

// ---------- chunked attention partials (no max-sub softmax), head-major ----------
__global__ __launch_bounds__(256) void attn_part_kernel(
    const float* __restrict__ Qh, const float* __restrict__ Kh, const float* __restrict__ Vh,
    const int* __restrict__ topIdx, float* __restrict__ Opart) {
  __shared__ int til[NSAMP];
  __shared__ alignas(16) float qs[NSAMP * 64];
  __shared__ alignas(16) float ps[NSAMP * 260];
  const int id = blockIdx.x;                   // 256, XCD-pinned
  const int xcd = id & 7, slot = id >> 3;
  const int bh = xcd * 8 + (slot & 7), c = slot >> 3;   // c in 0..3
  const int tid = threadIdx.x, wv = tid >> 6, lane = tid & 63;
  if (tid < NSAMP) til[tid] = topIdx[bh * NSAMP + tid];
  __syncthreads();
  for (int e = tid; e < NSAMP * 64; e += 256) {
    int i = e >> 6, d = e & 63;
    qs[e] = Qh[((size_t)bh << 16) + ((size_t)til[i] << 6) + d];
  }
  __syncthreads();
  {  // scores: thread = key in chunk
    const float* Kr = Kh + ((size_t)bh << 16) + ((size_t)(c * 256 + tid) << 6);
    float acc[NSAMP];
#pragma unroll
    for (int i = 0; i < NSAMP; ++i) acc[i] = 0.f;
    for (int c16 = 0; c16 < 16; ++c16) {
      float4 k4 = *(const float4*)(Kr + c16 * 4);
#pragma unroll
      for (int i = 0; i < NSAMP; ++i) {
        float4 q4 = *(const float4*)&qs[i * 64 + c16 * 4];
        acc[i] = fmaf(k4.x, q4.x, acc[i]);
        acc[i] = fmaf(k4.y, q4.y, acc[i]);
        acc[i] = fmaf(k4.z, q4.z, acc[i]);
        acc[i] = fmaf(k4.w, q4.w, acc[i]);
      }
    }
#pragma unroll
    for (int i = 0; i < NSAMP; ++i) ps[i * 260 + tid] = expf(acc[i] * 0.125f);
  }
  __syncthreads();
  float o[NSAMP], sacc[NSAMP];
#pragma unroll
  for (int i = 0; i < NSAMP; ++i) { o[i] = 0.f; sacc[i] = 0.f; }
  {  // PV: wave wv handles 64 keys; lane = d
    const float* Vb = Vh + ((size_t)bh << 16) + ((size_t)(c * 256) << 6) + lane;
    for (int j = 0; j < 64; ++j) {
      int kkl = wv * 64 + j;
      float vv = Vb[(size_t)kkl << 6];
#pragma unroll
      for (int i = 0; i < NSAMP; ++i) {
        float p = ps[i * 260 + kkl];
        o[i] = fmaf(p, vv, o[i]);
        sacc[i] += p;
      }
    }
  }
  __syncthreads();
  float* red = ps;
#pragma unroll
  for (int i = 0; i < NSAMP; ++i) {
    red[(wv * NSAMP + i) * 65 + lane] = o[i];
    if (lane == 0) red[(wv * NSAMP + i) * 65 + 64] = sacc[i];
  }
  __syncthreads();
  for (int e = tid; e < NSAMP * 65; e += 256) {
    int i = e / 65, d = e - i * 65;
    float s = red[(0 * NSAMP + i) * 65 + d] + red[(1 * NSAMP + i) * 65 + d] +
              red[(2 * NSAMP + i) * 65 + d] + red[(3 * NSAMP + i) * 65 + d];
    Opart[((size_t)(bh * NSAMP + i) * 4 + c) * 65 + d] = s;
  }
}

// ---------- combine chunks, divide, scatter into O ----------
__global__ __launch_bounds__(256) void attn_final_kernel(
    const float* __restrict__ Opart, const int* __restrict__ topIdx,
    unsigned short* __restrict__ Ob) {
  int e = blockIdx.x * 256 + threadIdx.x;   // 64*35*64 = 143360
  int d = e & 63, r = e >> 6;               // r = bh*35 + i
  int bh = r / NSAMP, i = r - bh * NSAMP;
  const float* base = Opart + (size_t)r * 4 * 65;
  float s = base[d] + base[65 + d] + base[130 + d] + base[195 + d];
  float den = base[64] + base[129] + base[194] + base[259];
  int b = bh >> 4, h = bh & 15;
  int til = topIdx[r];
  Ob[((size_t)b * SEQ + til) * EMB + h * 64 + d] = bf16b(s / den);
}

// ---------- BatchNorm over (B,S): stats then apply ----------
__global__ __launch_bounds__(256) void bnstats_kernel(
    const float* __restrict__ a, const float* __restrict__ bb, float* __restrict__ sums) {
  const int t = threadIdx.x, r0 = blockIdx.x << 5;
  float s1[4] = {0, 0, 0, 0}, s2[4] = {0, 0, 0, 0};
  for (int r = r0; r < r0 + 32; ++r) {
    const float* ar = a + (size_t)r * EMB;
    const float* br = bb + (size_t)r * EMB;
#pragma unroll
    for (int q = 0; q < 4; ++q) {
      float x = ar[t + (q << 8)] + br[t + (q << 8)];
      s1[q] += x; s2[q] = fmaf(x, x, s2[q]);
    }
  }
#pragma unroll
  for (int q = 0; q < 4; ++q) {
    atomicAdd(&sums[t + (q << 8)], s1[q]);
    atomicAdd(&sums[EMB + t + (q << 8)], s2[q]);
  }
}
__global__ void bnapply_kernel(
    const float* __restrict__ a, const float* __restrict__ bres,
    const float* __restrict__ sums, const float* __restrict__ g,
    const float* __restrict__ bet, float* __restrict__ outF, unsigned short* __restrict__ outB) {
  int i = blockIdx.x * 256 + threadIdx.x;
  int c = i & (EMB - 1);
  float mu = sums[c] * (1.f / 4096.f);
  float var = sums[EMB + c] * (1.f / 4096.f) - mu * mu;
  float x = a[i] + bres[i];
  float y = (x - mu) * rsqrtf(var + 1e-5f) * g[c] + bet[c];
  outF[i] = y;
  if (outB) outB[i] = bf16b(y);
}

// =====================================================================
extern "C" void kernel_launch(void* const* d_in, const int* in_sizes, int n_in,
                              void* d_out, int out_size, void* d_ws, size_t ws_size,
                              hipStream_t stream) {
  const float* tgt  = (const float*)d_in[0];
  const float* memi = (const float*)d_in[1];
  const float* sa_wq = (const float*)d_in[2];  const float* sa_bq = (const float*)d_in[3];
  const float* sa_wk = (const float*)d_in[4];  const float* sa_bk = (const float*)d_in[5];
  const float* sa_wv = (const float*)d_in[6];  const float* sa_bv = (const float*)d_in[7];
  const float* sa_wo = (const float*)d_in[8];  const float* sa_bo = (const float*)d_in[9];
  const float* ca_wq = (const float*)d_in[10]; const float* ca_bq = (const float*)d_in[11];
  const float* ca_wk = (const float*)d_in[12]; const float* ca_bk = (const float*)d_in[13];
  const float* ca_wv = (const float*)d_in[14]; const float* ca_bv = (const float*)d_in[15];
  const float* ca_wo = (const float*)d_in[16]; const float* ca_bo = (const float*)d_in[17];
  const float* w1 = (const float*)d_in[18];    const float* b1 = (const float*)d_in[19];
  const float* w2 = (const float*)d_in[20];    const float* b2 = (const float*)d_in[21];
  const float* bn1g = (const float*)d_in[22];  const float* bn1b = (const float*)d_in[23];
  const float* bn2g = (const float*)d_in[24];  const float* bn2b = (const float*)d_in[25];
  const float* bn3g = (const float*)d_in[26];  const float* bn3b = (const float*)d_in[27];

  char* wsb = (char*)d_ws;
  size_t off = 0;
  auto alloc = [&](size_t bytes) -> char* {
    char* p = wsb + off;
    off = (off + bytes + 255) & ~(size_t)255;
    return p;
  };
  unsigned short* WTqkv = (unsigned short*)alloc((size_t)3072 * 1024 * 2);
  unsigned short* WTosa = (unsigned short*)alloc((size_t)1024 * 1024 * 2);
  unsigned short* WTqca = (unsigned short*)alloc((size_t)1024 * 1024 * 2);
  unsigned short* WTkv  = (unsigned short*)alloc((size_t)2048 * 1024 * 2);
  unsigned short* WToca = (unsigned short*)alloc((size_t)1024 * 1024 * 2);
  unsigned short* WT1   = (unsigned short*)alloc((size_t)4096 * 1024 * 2);
  unsigned short* WT2   = (unsigned short*)alloc((size_t)1024 * 4096 * 2);
  float* qkvB = (float*)alloc(3072 * 4);
  float* kvB  = (float*)alloc(2048 * 4);
  unsigned short* tgtB = (unsigned short*)alloc((size_t)MROWS * EMB * 2);
  unsigned short* memB = (unsigned short*)alloc((size_t)MROWS * EMB * 2);
  unsigned short* x1B  = (unsigned short*)alloc((size_t)MROWS * EMB * 2);
  unsigned short* x2B  = (unsigned short*)alloc((size_t)MROWS * EMB * 2);
  unsigned short* OB   = (unsigned short*)alloc((size_t)MROWS * EMB * 2);
  unsigned short* HB   = (unsigned short*)alloc((size_t)MROWS * DFF * 2);
  float* QKVh = (float*)alloc((size_t)3 * 64 * 65536 * 4);   // head-major Q,K,V
  float* t2  = (float*)alloc((size_t)MROWS * EMB * 4);
  float* x1f = (float*)alloc((size_t)MROWS * EMB * 4);
  float* x2f = (float*)alloc((size_t)MROWS * EMB * 4);
  int* idxb  = (int*)alloc((size_t)2 * SEQ * NSAMP * 4);
  float* Mbuf = (float*)alloc((size_t)64 * 1024 * 4);
  int* topA = (int*)alloc(64 * NSAMP * 4);
  int* topB = (int*)alloc(64 * NSAMP * 4);
  float* vmean = (float*)alloc(64 * 64 * 4);
  float* sums = (float*)alloc(2 * EMB * 4);
  float* Opart = (float*)alloc((size_t)64 * NSAMP * 4 * 65 * 4);
  if (off > ws_size) return;

  float* Qh = QKVh;
  float* Kh = QKVh + ((size_t)1 << 22);
  float* Vh = QKVh + ((size_t)2 << 22);

  auto GEMM = [&](const unsigned short* A, int lda, const unsigned short* BT, int ldb,
                  float* C, int ldc, const float* bias, int M_, int N_, int K_) {
    dim3 g(N_ >> 7, M_ >> 7);
    gemm_kernel<0><<<g, 256, 0, stream>>>(A, lda, BT, ldb, C, ldc, nullptr, 0, bias, K_, 0);
  };
  auto TR = [&](const float* src, unsigned short* dst, int K_, int N_) {
    dim3 g(N_ / 32, K_ / 32), bl(32, 8);
    transpose_kernel<<<g, bl, 0, stream>>>(src, dst, K_, N_);
  };
  auto ATTN = [&](const int* top) {
    (void)hipMemsetAsync(vmean, 0, 64 * 64 * 4, stream);
    vmean_kernel<<<512, 64, 0, stream>>>(Vh, vmean);
    fillO_kernel<<<16384, 256, 0, stream>>>(vmean, OB);
    attn_part_kernel<<<256, 256, 0, stream>>>(Qh, Kh, Vh, top, Opart);
    attn_final_kernel<<<560, 256, 0, stream>>>(Opart, top, OB);
  };

  // ---- prep ----
  idx_kernel<<<280, 256, 0, stream>>>(idxb);
  f2b_kernel<<<4096, 256, 0, stream>>>(tgt, tgtB, MROWS * EMB / 4);
  f2b_kernel<<<4096, 256, 0, stream>>>(memi, memB, MROWS * EMB / 4);
  TR(sa_wq, WTqkv, 1024, 1024);
  TR(sa_wk, WTqkv + (size_t)1024 * 1024, 1024, 1024);
  TR(sa_wv, WTqkv + (size_t)2048 * 1024, 1024, 1024);
  TR(sa_wo, WTosa, 1024, 1024);
  TR(ca_wq, WTqca, 1024, 1024);
  TR(ca_wk, WTkv, 1024, 1024);
  TR(ca_wv, WTkv + (size_t)1024 * 1024, 1024, 1024);
  TR(ca_wo, WToca, 1024, 1024);
  TR(w1, WT1, 1024, 4096);
  TR(w2, WT2, 4096, 1024);
  biascat_kernel<<<4, 256, 0, stream>>>(sa_bq, sa_bk, sa_bv, ca_bk, ca_bv, qkvB, kvB);

  // ---- layer A: self-attention ----
  gemm256_kernel<2><<<dim3(3072 >> 8, MROWS >> 8), 512, 0, stream>>>(
      tgtB, 1024, WTqkv, 1024, QKVh, 0, nullptr, 0, qkvB, 1024, 0);
  m6_kernel<<<16384, 256, 0, stream>>>(Qh, Kh, idxb, Mbuf);
  topk2_kernel<<<64, 64, 0, stream>>>(Mbuf, topA);
  ATTN(topA);
  GEMM(OB, 1024, WTosa, 1024, t2, 1024, sa_bo, MROWS, 1024, 1024);
  (void)hipMemsetAsync(sums, 0, 2 * EMB * 4, stream);
  bnstats_kernel<<<128, 256, 0, stream>>>(tgt, t2, sums);
  bnapply_kernel<<<16384, 256, 0, stream>>>(tgt, t2, sums, bn1g, bn1b, x1f, x1B);

  // ---- layer B: cross-attention ----
  gemm_kernel<2><<<dim3(1024 >> 7, MROWS >> 7), 256, 0, stream>>>(
      x1B, 1024, WTqca, 1024, QKVh, 0, nullptr, 0, ca_bq, 1024, 0);
  gemm_kernel<2><<<dim3(2048 >> 7, MROWS >> 7), 256, 0, stream>>>(
      memB, 1024, WTkv, 1024, QKVh, 0, nullptr, 0, kvB, 1024, 1024);
  m6_kernel<<<16384, 256, 0, stream>>>(Qh, Kh, idxb + SEQ * NSAMP, Mbuf);
  topk2_kernel<<<64, 64, 0, stream>>>(Mbuf, topB);
  ATTN(topB);
  GEMM(OB, 1024, WToca, 1024, t2, 1024, ca_bo, MROWS, 1024, 1024);
  (void)hipMemsetAsync(sums, 0, 2 * EMB * 4, stream);
  bnstats_kernel<<<128, 256, 0, stream>>>(x1f, t2, sums);
  bnapply_kernel<<<16384, 256, 0, stream>>>(x1f, t2, sums, bn2g, bn2b, x2f, x2B);

  // ---- FFN + bn3 ----
  gemm256_kernel<1><<<dim3(DFF >> 8, MROWS >> 8), 512, 0, stream>>>(
      x2B, 1024, WT1, 1024, nullptr, 0, HB, DFF, b1, 1024, 0);
  GEMM(HB, 4096, WT2, 4096, t2, 1024, b2, MROWS, 1024, 4096);
  (void)hipMemsetAsync(sums, 0, 2 * EMB * 4, stream);
  bnstats_kernel<<<128, 256, 0, stream>>>(x2f, t2, sums);
  bnapply_kernel<<<16384, 256, 0, stream>>>(x2f, t2, sums, bn3g, bn3b, (float*)d_out, nullptr);
}

// Round 8
// 870.413 us; speedup vs baseline: 1.1934x; 1.1934x over previous
//
#include <hip/hip_runtime.h>
#include <cstdint>

// ---------------- problem constants ----------------
#define BQ 4
#define SEQ 1024
#define EMB 1024
#define NH 16
#define DKH 64
#define DFF 4096
#define MROWS 4096          // BQ*SEQ
#define NSAMP 35            // sample_k == n_top == 35

typedef int   i32x4 __attribute__((ext_vector_type(4)));
typedef float f32x4 __attribute__((ext_vector_type(4)));
typedef short s16x8 __attribute__((ext_vector_type(8)));
typedef __bf16 b16x8 __attribute__((ext_vector_type(8)));

// ---------- bf16 helpers ----------
__device__ __forceinline__ unsigned short bf16b(float f) {
  unsigned u = __builtin_bit_cast(unsigned, f);
  return (unsigned short)((u + 0x7FFFu + ((u >> 16) & 1u)) >> 16);
}
__device__ __forceinline__ float b2f(unsigned short v) {
  return __builtin_bit_cast(float, (unsigned)v << 16);
}
__device__ __forceinline__ float blo(unsigned u) {
  return __builtin_bit_cast(float, u << 16);
}
__device__ __forceinline__ float bhi(unsigned u) {
  return __builtin_bit_cast(float, u & 0xFFFF0000u);
}

// ---------- MFMA wrapper: SFINAE over operand element type ----------
template <typename T> struct other_vec { using type = b16x8; };
template <> struct other_vec<b16x8>    { using type = s16x8; };

template <typename T>
__device__ __forceinline__ auto mfma_try(T a, T b, f32x4 c, int)
    -> decltype(__builtin_amdgcn_mfma_f32_16x16x32_bf16(a, b, c, 0, 0, 0)) {
  return __builtin_amdgcn_mfma_f32_16x16x32_bf16(a, b, c, 0, 0, 0);
}
template <typename T>
__device__ __forceinline__ f32x4 mfma_try(T a, T b, f32x4 c, long) {
  using U = typename other_vec<T>::type;
  U a2 = __builtin_bit_cast(U, a);
  U b2 = __builtin_bit_cast(U, b);
  return __builtin_amdgcn_mfma_f32_16x16x32_bf16(a2, b2, c, 0, 0, 0);
}
__device__ __forceinline__ f32x4 mfma_bf16(i32x4 a, i32x4 b, f32x4 c) {
  s16x8 as = __builtin_bit_cast(s16x8, a);
  s16x8 bs = __builtin_bit_cast(s16x8, b);
  return mfma_try(as, bs, c, 0);
}

// ---------- async global->LDS (16B per lane) ----------
typedef const __attribute__((address_space(1))) void GV;
typedef __attribute__((address_space(3))) void LV;
__device__ __forceinline__ void gload_lds16(const void* g, void* l) {
  __builtin_amdgcn_global_load_lds((GV*)(uintptr_t)g,
                                   (LV*)(unsigned)(uintptr_t)l, 16, 0, 0);
}

// ---------- Threefry-2x32 (20 rounds), JAX-compatible ----------
__device__ __forceinline__ void tf2x32(unsigned k0, unsigned k1, unsigned x0, unsigned x1,
                                       unsigned& o0, unsigned& o1) {
  unsigned ks2 = k0 ^ k1 ^ 0x1BD11BDAu;
  x0 += k0; x1 += k1;
#define TFR(r) { x0 += x1; x1 = (x1 << r) | (x1 >> (32 - r)); x1 ^= x0; }
  TFR(13) TFR(15) TFR(26) TFR(6)   x0 += k1;  x1 += ks2 + 1u;
  TFR(17) TFR(29) TFR(16) TFR(24)  x0 += ks2; x1 += k0 + 2u;
  TFR(13) TFR(15) TFR(26) TFR(6)   x0 += k0;  x1 += k1 + 3u;
  TFR(17) TFR(29) TFR(16) TFR(24)  x0 += k1;  x1 += ks2 + 4u;
  TFR(13) TFR(15) TFR(26) TFR(6)   x0 += ks2; x1 += k0 + 5u;
#undef TFR
  o0 = x0; o1 = x1;
}

__global__ void idx_kernel(int* __restrict__ out) {
  int t = blockIdx.x * 256 + threadIdx.x;       // 0..71679
  if (t >= 2 * SEQ * NSAMP) return;
  int sel = t >= SEQ * NSAMP;
  int i = sel ? t - SEQ * NSAMP : t;
  unsigned s0, s1, d0, d1;
  tf2x32(0u, 42u, 0u, 0u, s0, s1);              // k1
  tf2x32(0u, 42u, 0u, 1u, d0, d1);              // k2
  unsigned key0 = sel ? d0 : s0, key1 = sel ? d1 : s1;
  unsigned o0, o1;
  tf2x32(key0, key1, 0u, (unsigned)i, o0, o1);
  out[t] = (int)((o0 ^ o1) & 1023u);
}

// ---------- fp32 -> bf16 elementwise ----------
__global__ void f2b_kernel(const float* __restrict__ in, unsigned short* __restrict__ out, int n4) {
  int i = blockIdx.x * 256 + threadIdx.x;
  if (i >= n4) return;
  float4 v = ((const float4*)in)[i];
  uint2 p;
  p.x = (unsigned)bf16b(v.x) | ((unsigned)bf16b(v.y) << 16);
  p.y = (unsigned)bf16b(v.z) | ((unsigned)bf16b(v.w) << 16);
  ((uint2*)out)[i] = p;
}

// ---------- W (KxN f32) -> WT (NxK bf16) ----------
__global__ void transpose_kernel(const float* __restrict__ W, unsigned short* __restrict__ WT,
                                 int K, int N) {
  __shared__ float tile[32][33];
  int n0 = blockIdx.x * 32, k0 = blockIdx.y * 32;
  int tx = threadIdx.x, ty = threadIdx.y;       // 32 x 8
#pragma unroll
  for (int r = 0; r < 4; ++r)
    tile[ty * 4 + r][tx] = W[(size_t)(k0 + ty * 4 + r) * N + n0 + tx];
  __syncthreads();
#pragma unroll
  for (int r = 0; r < 4; ++r) {
    int n = n0 + ty * 4 + r, k = k0 + tx;
    WT[(size_t)n * K + k] = bf16b(tile[tx][ty * 4 + r]);
  }
}

__global__ void biascat_kernel(const float* q, const float* k, const float* v,
                               const float* ck, const float* cv,
                               float* qkvB, float* kvB) {
  int t = blockIdx.x * 256 + threadIdx.x;
  if (t < 1024) {
    qkvB[t] = q[t]; qkvB[1024 + t] = k[t]; qkvB[2048 + t] = v[t];
    kvB[t] = ck[t]; kvB[1024 + t] = cv[t];
  }
}

// ---------- bf16 MFMA GEMM, 128x128 tile, BK=32, 256 thr ----------
// EPI 0: C=acc+bias (f32, row-major ldc). EPI 1: Cb = bf16(gelu(acc+bias)).
// EPI 2: head-major bf16 QKV scatter: Cb[which][bh][l][d], which=(col+colofs)>>10.
template <int EPI>
__global__ __launch_bounds__(256) void gemm_kernel(
    const unsigned short* __restrict__ A, int lda,
    const unsigned short* __restrict__ BT, int ldb,
    float* __restrict__ C, int ldc,
    unsigned short* __restrict__ Cb, int ldcb,
    const float* __restrict__ bias, int K, int colofs) {
  __shared__ alignas(16) unsigned short As[128 * 32];
  __shared__ alignas(16) unsigned short Bs[128 * 32];
  const int tid = threadIdx.x;
  const int bm = blockIdx.y << 7, bn = blockIdx.x << 7;
  const int wave = tid >> 6, lane = tid & 63;
  const int wm = (wave & 1) << 6, wn = (wave >> 1) << 6;
  const int lr = lane & 15, lg = lane >> 4;

  f32x4 acc[4][4];
#pragma unroll
  for (int i = 0; i < 4; ++i)
#pragma unroll
    for (int j = 0; j < 4; ++j) acc[i][j] = f32x4{0.f, 0.f, 0.f, 0.f};

  const int trow = tid >> 2, tcol = (tid & 3) << 3;
  const unsigned short* Ag = A + (size_t)(bm + trow) * lda + tcol;
  const unsigned short* Bg = BT + (size_t)(bn + trow) * ldb + tcol;
  unsigned short* Al = &As[tid * 8];
  unsigned short* Bl = &Bs[tid * 8];

  for (int kt = 0; kt < K; kt += 32) {
    __syncthreads();
    gload_lds16(Ag + kt, Al);
    gload_lds16(Ag + (size_t)64 * lda + kt, Al + 2048);
    gload_lds16(Bg + kt, Bl);
    gload_lds16(Bg + (size_t)64 * ldb + kt, Bl + 2048);
    __syncthreads();
    i32x4 af[4], bf[4];
#pragma unroll
    for (int i = 0; i < 4; ++i)
      af[i] = *(const i32x4*)&As[(wm + i * 16 + lr) * 32 + lg * 8];
#pragma unroll
    for (int j = 0; j < 4; ++j)
      bf[j] = *(const i32x4*)&Bs[(wn + j * 16 + lr) * 32 + lg * 8];
#pragma unroll
    for (int i = 0; i < 4; ++i)
#pragma unroll
      for (int j = 0; j < 4; ++j)
        acc[i][j] = mfma_bf16(af[i], bf[j], acc[i][j]);
  }
#pragma unroll
  for (int i = 0; i < 4; ++i)
#pragma unroll
    for (int j = 0; j < 4; ++j)
#pragma unroll
      for (int r = 0; r < 4; ++r) {
        int row = bm + wm + i * 16 + lg * 4 + r;
        int col = bn + wn + j * 16 + lr;
        float v = acc[i][j][r] + bias[col];
        if constexpr (EPI == 0) {
          C[(size_t)row * ldc + col] = v;
        } else if constexpr (EPI == 1) {
          float gl = 0.5f * v * (1.f + erff(v * 0.70710678118654752f));
          Cb[(size_t)row * ldcb + col] = bf16b(gl);
        } else {
          int cc = col + colofs;
          int which = cc >> 10;
          int h = (cc >> 6) & 15;
          int d = col & 63;
          int b = row >> 10, l = row & 1023;
          Cb[((size_t)which << 22) + (((b << 4) + h) << 16) + (l << 6) + d] = bf16b(v);
        }
      }
}

// ---------- M = max_s(q.k_samp) - sum_s(q.k_samp)/1024, head-major bf16 ----------
// One query per wave + XCD pinning (16384%8==0 -> id&7 == XCD; 8 bh per XCD;
// per-XCD working set 8 bh x (128KB K + 128KB Q) = 2 MB << L2).
__global__ __launch_bounds__(256) void m6_kernel(
    const unsigned short* __restrict__ Qh, const unsigned short* __restrict__ Kh,
    const int* __restrict__ idx, float* __restrict__ Mout) {
  __shared__ float dots[4][36];
  const int id = blockIdx.x;
  const int xcd = id & 7, slot = id >> 3;            // slot 0..2047
  const int bh = xcd * 8 + (slot & 7);               // 8 bh per XCD
  const int qbase = (slot >> 3) << 2;                // 256 chunks x 4 queries
  const int tid = threadIdx.x, wv = tid >> 6, lane = tid & 63;
  const int l = qbase + wv;
  const unsigned short* Qr = Qh + ((size_t)bh << 16) + ((size_t)l << 6);
  if (lane < NSAMP) {
    const int s = idx[l * NSAMP + lane];
    const unsigned short* Kr = Kh + ((size_t)bh << 16) + ((size_t)s << 6);
    float pa0 = 0.f, pa1 = 0.f, pa2 = 0.f, pa3 = 0.f;
#pragma unroll
    for (int c8 = 0; c8 < 8; ++c8) {                 // 8 chunks of 8 bf16
      uint4 kk = *(const uint4*)(Kr + c8 * 8);
      uint4 qq = *(const uint4*)(Qr + c8 * 8);       // uniform -> broadcast
      pa0 = fmaf(blo(kk.x), blo(qq.x), pa0);
      pa1 = fmaf(bhi(kk.x), bhi(qq.x), pa1);
      pa2 = fmaf(blo(kk.y), blo(qq.y), pa2);
      pa3 = fmaf(bhi(kk.y), bhi(qq.y), pa3);
      pa0 = fmaf(blo(kk.z), blo(qq.z), pa0);
      pa1 = fmaf(bhi(kk.z), bhi(qq.z), pa1);
      pa2 = fmaf(blo(kk.w), blo(qq.w), pa2);
      pa3 = fmaf(bhi(kk.w), bhi(qq.w), pa3);
    }
    dots[wv][lane] = (pa0 + pa1) + (pa2 + pa3);
  }
  __syncthreads();
  if (tid < 16) {
    int q = tid >> 2, cp = tid & 3;
    int sb = cp * 9, se = (cp == 3) ? NSAMP : (sb + 9);
    float mx = -__builtin_inff(), sm = 0.f;
    for (int s = sb; s < se; ++s) {
      float v = dots[q][s];
      mx = fmaxf(mx, v);
      sm += v;
    }
    mx = fmaxf(mx, __shfl_xor(mx, 1, 64)); sm += __shfl_xor(sm, 1, 64);
    mx = fmaxf(mx, __shfl_xor(mx, 2, 64)); sm += __shfl_xor(sm, 2, 64);
    if (cp == 0) Mout[bh * 1024 + qbase + q] = mx - sm * (1.f / 1024.f);
  }
}

// ---------- single-wave top-35 per (b,h) ----------
__device__ __forceinline__ void amax2(float& v, int& id, float v2, int id2) {
  if (v2 > v || (v2 == v && id2 < id)) { v = v2; id = id2; }
}
__global__ __launch_bounds__(64) void topk2_kernel(
    const float* __restrict__ Mbuf, int* __restrict__ topOut) {
  const int bh = blockIdx.x, t = threadIdx.x;
  float v[16]; int li[16];
#pragma unroll
  for (int r = 0; r < 16; ++r) { int l = t + (r << 6); v[r] = Mbuf[bh * 1024 + l]; li[r] = l; }
  for (int it = 0; it < NSAMP; ++it) {
    float bv = v[0]; int bi = li[0];
#pragma unroll
    for (int r = 1; r < 16; ++r) amax2(bv, bi, v[r], li[r]);
#pragma unroll
    for (int m = 1; m < 64; m <<= 1) {
      float ov = __shfl_xor(bv, m, 64); int oi = __shfl_xor(bi, m, 64);
      amax2(bv, bi, ov, oi);
    }
    if (t == 0) topOut[bh * NSAMP + it] = bi;
#pragma unroll
    for (int r = 0; r < 16; ++r) if (li[r] == bi) v[r] = -__builtin_inff();
  }
}

// ---------- v sums per (b,h,d), head-major bf16 ----------
__global__ void vmean_kernel(const unsigned short* __restrict__ Vh, float* __restrict__ vmean) {
  const int g = blockIdx.x, bh = g >> 3, ch = g & 7;
  const int d = threadIdx.x;
  const unsigned short* Vb = Vh + ((size_t)bh << 16) + (ch * 128 << 6) + d;
  float s = 0.f;
  for (int l = 0; l < 128; ++l) s += b2f(Vb[l << 6]);
  atomicAdd(&vmean[bh * 64 + d], s);
}

// ---------- fill O with broadcast v-mean (bf16) ----------
__global__ void fillO_kernel(const float* __restrict__ vmean, unsigned short* __restrict__ Ob) {
  int i = blockIdx.x * 256 + threadIdx.x;     // 4096*1024
  int e = i & 1023, b = i >> 20;
  int h = e >> 6, d = e & 63;
  Ob[i] = bf16b(vmean[((b << 4) + h) * 64 + d] * (1.f / 1024.f));
}

// ---------- chunked attention partials (no max-sub softmax), head-major bf16 ----------
__global__ __launch_bounds__(256) void attn_part_kernel(
    const unsigned short* __restrict__ Qh, const unsigned short* __restrict__ Kh,
    const unsigned short* __restrict__ Vh,
    const int* __restrict__ topIdx, float* __restrict__ Opart) {
  __shared__ int til[NSAMP];
  __shared__ alignas(16) float qs[NSAMP * 64];
  __shared__ alignas(16) float ps[NSAMP * 260];
  const int id = blockIdx.x;                   // 256, XCD-pinned
  const int xcd = id & 7, slot = id >> 3;
  const int bh = xcd * 8 + (slot & 7), c = slot >> 3;   // c in 0..3
  const int tid = threadIdx.x, wv = tid >> 6, lane = tid & 63;
  if (tid < NSAMP) til[tid] = topIdx[bh * NSAMP + tid];
  __syncthreads();
  for (int e = tid; e < NSAMP * 64; e += 256) {
    int i = e >> 6, d = e & 63;
    qs[e] = b2f(Qh[((size_t)bh << 16) + ((size_t)til[i] << 6) + d]);
  }
  __syncthreads();
  {  // scores: thread = key in chunk
    const unsigned short* Kr = Kh + ((size_t)bh << 16) + ((size_t)(c * 256 + tid) << 6);
    float acc[NSAMP];
#pragma unroll
    for (int i = 0; i < NSAMP; ++i) acc[i] = 0.f;
    for (int c8 = 0; c8 < 8; ++c8) {
      uint4 kk = *(const uint4*)(Kr + c8 * 8);
      float k0 = blo(kk.x), k1 = bhi(kk.x), k2 = blo(kk.y), k3 = bhi(kk.y);
      float k4 = blo(kk.z), k5 = bhi(kk.z), k6 = blo(kk.w), k7 = bhi(kk.w);
#pragma unroll
      for (int i = 0; i < NSAMP; ++i) {
        float4 qa = *(const float4*)&qs[i * 64 + c8 * 8];
        float4 qb = *(const float4*)&qs[i * 64 + c8 * 8 + 4];
        acc[i] = fmaf(k0, qa.x, acc[i]);
        acc[i] = fmaf(k1, qa.y, acc[i]);
        acc[i] = fmaf(k2, qa.z, acc[i]);
        acc[i] = fmaf(k3, qa.w, acc[i]);
        acc[i] = fmaf(k4, qb.x, acc[i]);
        acc[i] = fmaf(k5, qb.y, acc[i]);
        acc[i] = fmaf(k6, qb.z, acc[i]);
        acc[i] = fmaf(k7, qb.w, acc[i]);
      }
    }
#pragma unroll
    for (int i = 0; i < NSAMP; ++i) ps[i * 260 + tid] = expf(acc[i] * 0.125f);
  }
  __syncthreads();
  float o[NSAMP], sacc[NSAMP];
#pragma unroll
  for (int i = 0; i < NSAMP; ++i) { o[i] = 0.f; sacc[i] = 0.f; }
  {  // PV: wave wv handles 64 keys; lane = d
    const unsigned short* Vb = Vh + ((size_t)bh << 16) + ((size_t)(c * 256) << 6) + lane;
    for (int j = 0; j < 64; ++j) {
      int kkl = wv * 64 + j;
      float vv = b2f(Vb[(size_t)kkl << 6]);
#pragma unroll
      for (int i = 0; i < NSAMP; ++i) {
        float p = ps[i * 260 + kkl];
        o[i] = fmaf(p, vv, o[i]);
        sacc[i] += p;
      }
    }
  }
  __syncthreads();
  float* red = ps;
#pragma unroll
  for (int i = 0; i < NSAMP; ++i) {
    red[(wv * NSAMP + i) * 65 + lane] = o[i];
    if (lane == 0) red[(wv * NSAMP + i) * 65 + 64] = sacc[i];
  }
  __syncthreads();
  for (int e = tid; e < NSAMP * 65; e += 256) {
    int i = e / 65, d = e - i * 65;
    float s = red[(0 * NSAMP + i) * 65 + d] + red[(1 * NSAMP + i) * 65 + d] +
              red[(2 * NSAMP + i) * 65 + d] + red[(3 * NSAMP + i) * 65 + d];
    Opart[((size_t)(bh * NSAMP + i) * 4 + c) * 65 + d] = s;
  }
}

// ---------- combine chunks, divide, scatter into O ----------
__global__ __launch_bounds__(256) void attn_final_kernel(
    const float* __restrict__ Opart, const int* __restrict__ topIdx,
    unsigned short* __restrict__ Ob) {
  int e = blockIdx.x * 256 + threadIdx.x;   // 64*35*64 = 143360
  int d = e & 63, r = e >> 6;               // r = bh*35 + i
  int bh = r / NSAMP, i = r - bh * NSAMP;
  const float* base = Opart + (size_t)r * 4 * 65;
  float s = base[d] + base[65 + d] + base[130 + d] + base[195 + d];
  float den = base[64] + base[129] + base[194] + base[259];
  int b = bh >> 4, h = bh & 15;
  int til = topIdx[r];
  Ob[((size_t)b * SEQ + til) * EMB + h * 64 + d] = bf16b(s / den);
}

// ---------- BatchNorm over (B,S): stats then apply ----------
__global__ __launch_bounds__(256) void bnstats_kernel(
    const float* __restrict__ a, const float* __restrict__ bb, float* __restrict__ sums) {
  const int t = threadIdx.x, r0 = blockIdx.x << 5;
  float s1[4] = {0, 0, 0, 0}, s2[4] = {0, 0, 0, 0};
  for (int r = r0; r < r0 + 32; ++r) {
    const float* ar = a + (size_t)r * EMB;
    const float* br = bb + (size_t)r * EMB;
#pragma unroll
    for (int q = 0; q < 4; ++q) {
      float x = ar[t + (q << 8)] + br[t + (q << 8)];
      s1[q] += x; s2[q] = fmaf(x, x, s2[q]);
    }
  }
#pragma unroll
  for (int q = 0; q < 4; ++q) {
    atomicAdd(&sums[t + (q << 8)], s1[q]);
    atomicAdd(&sums[EMB + t + (q << 8)], s2[q]);
  }
}
__global__ void bnapply_kernel(
    const float* __restrict__ a, const float* __restrict__ bres,
    const float* __restrict__ sums, const float* __restrict__ g,
    const float* __restrict__ bet, float* __restrict__ outF, unsigned short* __restrict__ outB) {
  int i = blockIdx.x * 256 + threadIdx.x;
  int c = i & (EMB - 1);
  float mu = sums[c] * (1.f / 4096.f);
  float var = sums[EMB + c] * (1.f / 4096.f) - mu * mu;
  float x = a[i] + bres[i];
  float y = (x - mu) * rsqrtf(var + 1e-5f) * g[c] + bet[c];
  outF[i] = y;
  if (outB) outB[i] = bf16b(y);
}

// =====================================================================
extern "C" void kernel_launch(void* const* d_in, const int* in_sizes, int n_in,
                              void* d_out, int out_size, void* d_ws, size_t ws_size,
                              hipStream_t stream) {
  const float* tgt  = (const float*)d_in[0];
  const float* memi = (const float*)d_in[1];
  const float* sa_wq = (const float*)d_in[2];  const float* sa_bq = (const float*)d_in[3];
  const float* sa_wk = (const float*)d_in[4];  const float* sa_bk = (const float*)d_in[5];
  const float* sa_wv = (const float*)d_in[6];  const float* sa_bv = (const float*)d_in[7];
  const float* sa_wo = (const float*)d_in[8];  const float* sa_bo = (const float*)d_in[9];
  const float* ca_wq = (const float*)d_in[10]; const float* ca_bq = (const float*)d_in[11];
  const float* ca_wk = (const float*)d_in[12]; const float* ca_bk = (const float*)d_in[13];
  const float* ca_wv = (const float*)d_in[14]; const float* ca_bv = (const float*)d_in[15];
  const float* ca_wo = (const float*)d_in[16]; const float* ca_bo = (const float*)d_in[17];
  const float* w1 = (const float*)d_in[18];    const float* b1 = (const float*)d_in[19];
  const float* w2 = (const float*)d_in[20];    const float* b2 = (const float*)d_in[21];
  const float* bn1g = (const float*)d_in[22];  const float* bn1b = (const float*)d_in[23];
  const float* bn2g = (const float*)d_in[24];  const float* bn2b = (const float*)d_in[25];
  const float* bn3g = (const float*)d_in[26];  const float* bn3b = (const float*)d_in[27];

  char* wsb = (char*)d_ws;
  size_t off = 0;
  auto alloc = [&](size_t bytes) -> char* {
    char* p = wsb + off;
    off = (off + bytes + 255) & ~(size_t)255;
    return p;
  };
  unsigned short* WTqkv = (unsigned short*)alloc((size_t)3072 * 1024 * 2);
  unsigned short* WTosa = (unsigned short*)alloc((size_t)1024 * 1024 * 2);
  unsigned short* WTqca = (unsigned short*)alloc((size_t)1024 * 1024 * 2);
  unsigned short* WTkv  = (unsigned short*)alloc((size_t)2048 * 1024 * 2);
  unsigned short* WToca = (unsigned short*)alloc((size_t)1024 * 1024 * 2);
  unsigned short* WT1   = (unsigned short*)alloc((size_t)4096 * 1024 * 2);
  unsigned short* WT2   = (unsigned short*)alloc((size_t)1024 * 4096 * 2);
  float* qkvB = (float*)alloc(3072 * 4);
  float* kvB  = (float*)alloc(2048 * 4);
  unsigned short* tgtB = (unsigned short*)alloc((size_t)MROWS * EMB * 2);
  unsigned short* memB = (unsigned short*)alloc((size_t)MROWS * EMB * 2);
  unsigned short* x1B  = (unsigned short*)alloc((size_t)MROWS * EMB * 2);
  unsigned short* x2B  = (unsigned short*)alloc((size_t)MROWS * EMB * 2);
  unsigned short* OB   = (unsigned short*)alloc((size_t)MROWS * EMB * 2);
  unsigned short* HB   = (unsigned short*)alloc((size_t)MROWS * DFF * 2);
  unsigned short* QKVhB = (unsigned short*)alloc((size_t)3 * 64 * 65536 * 2);  // bf16 head-major
  float* t2  = (float*)alloc((size_t)MROWS * EMB * 4);
  float* x1f = (float*)alloc((size_t)MROWS * EMB * 4);
  float* x2f = (float*)alloc((size_t)MROWS * EMB * 4);
  int* idxb  = (int*)alloc((size_t)2 * SEQ * NSAMP * 4);
  float* Mbuf = (float*)alloc((size_t)64 * 1024 * 4);
  int* topA = (int*)alloc(64 * NSAMP * 4);
  int* topB = (int*)alloc(64 * NSAMP * 4);
  float* vmean = (float*)alloc(64 * 64 * 4);
  float* sums = (float*)alloc(2 * EMB * 4);
  float* Opart = (float*)alloc((size_t)64 * NSAMP * 4 * 65 * 4);
  if (off > ws_size) return;

  unsigned short* Qh = QKVhB;
  unsigned short* Kh = QKVhB + ((size_t)1 << 22);
  unsigned short* Vh = QKVhB + ((size_t)2 << 22);

  auto GEMM = [&](const unsigned short* A, int lda, const unsigned short* BT, int ldb,
                  float* C, int ldc, const float* bias, int M_, int N_, int K_) {
    dim3 g(N_ >> 7, M_ >> 7);
    gemm_kernel<0><<<g, 256, 0, stream>>>(A, lda, BT, ldb, C, ldc, nullptr, 0, bias, K_, 0);
  };
  auto GEMMH = [&](const unsigned short* A, const unsigned short* BT,
                   const float* bias, int N_, int K_, int colofs) {
    dim3 g(N_ >> 7, MROWS >> 7);
    gemm_kernel<2><<<g, 256, 0, stream>>>(A, K_, BT, K_, nullptr, 0, QKVhB, 0, bias, K_, colofs);
  };
  auto TR = [&](const float* src, unsigned short* dst, int K_, int N_) {
    dim3 g(N_ / 32, K_ / 32), bl(32, 8);
    transpose_kernel<<<g, bl, 0, stream>>>(src, dst, K_, N_);
  };
  auto ATTN = [&](const int* top) {
    (void)hipMemsetAsync(vmean, 0, 64 * 64 * 4, stream);
    vmean_kernel<<<512, 64, 0, stream>>>(Vh, vmean);
    fillO_kernel<<<16384, 256, 0, stream>>>(vmean, OB);
    attn_part_kernel<<<256, 256, 0, stream>>>(Qh, Kh, Vh, top, Opart);
    attn_final_kernel<<<560, 256, 0, stream>>>(Opart, top, OB);
  };

  // ---- prep ----
  idx_kernel<<<280, 256, 0, stream>>>(idxb);
  f2b_kernel<<<4096, 256, 0, stream>>>(tgt, tgtB, MROWS * EMB / 4);
  f2b_kernel<<<4096, 256, 0, stream>>>(memi, memB, MROWS * EMB / 4);
  TR(sa_wq, WTqkv, 1024, 1024);
  TR(sa_wk, WTqkv + (size_t)1024 * 1024, 1024, 1024);
  TR(sa_wv, WTqkv + (size_t)2048 * 1024, 1024, 1024);
  TR(sa_wo, WTosa, 1024, 1024);
  TR(ca_wq, WTqca, 1024, 1024);
  TR(ca_wk, WTkv, 1024, 1024);
  TR(ca_wv, WTkv + (size_t)1024 * 1024, 1024, 1024);
  TR(ca_wo, WToca, 1024, 1024);
  TR(w1, WT1, 1024, 4096);
  TR(w2, WT2, 4096, 1024);
  biascat_kernel<<<4, 256, 0, stream>>>(sa_bq, sa_bk, sa_bv, ca_bk, ca_bv, qkvB, kvB);

  // ---- layer A: self-attention ----
  GEMMH(tgtB, WTqkv, qkvB, 3072, 1024, 0);
  m6_kernel<<<16384, 256, 0, stream>>>(Qh, Kh, idxb, Mbuf);
  topk2_kernel<<<64, 64, 0, stream>>>(Mbuf, topA);
  ATTN(topA);
  GEMM(OB, 1024, WTosa, 1024, t2, 1024, sa_bo, MROWS, 1024, 1024);
  (void)hipMemsetAsync(sums, 0, 2 * EMB * 4, stream);
  bnstats_kernel<<<128, 256, 0, stream>>>(tgt, t2, sums);
  bnapply_kernel<<<16384, 256, 0, stream>>>(tgt, t2, sums, bn1g, bn1b, x1f, x1B);

  // ---- layer B: cross-attention ----
  GEMMH(x1B, WTqca, ca_bq, 1024, 1024, 0);
  GEMMH(memB, WTkv, kvB, 2048, 1024, 1024);
  m6_kernel<<<16384, 256, 0, stream>>>(Qh, Kh, idxb + SEQ * NSAMP, Mbuf);
  topk2_kernel<<<64, 64, 0, stream>>>(Mbuf, topB);
  ATTN(topB);
  GEMM(OB, 1024, WToca, 1024, t2, 1024, ca_bo, MROWS, 1024, 1024);
  (void)hipMemsetAsync(sums, 0, 2 * EMB * 4, stream);
  bnstats_kernel<<<128, 256, 0, stream>>>(x1f, t2, sums);
  bnapply_kernel<<<16384, 256, 0, stream>>>(x1f, t2, sums, bn2g, bn2b, x2f, x2B);

  // ---- FFN + bn3 ----
  gemm_kernel<1><<<dim3(DFF >> 7, MROWS >> 7), 256, 0, stream>>>(
      x2B, 1024, WT1, 1024, nullptr, 0, HB, DFF, b1, 1024, 0);
  GEMM(HB, 4096, WT2, 4096, t2, 1024, b2, MROWS, 1024, 4096);
  (void)hipMemsetAsync(sums, 0, 2 * EMB * 4, stream);
  bnstats_kernel<<<128, 256, 0, stream>>>(x2f, t2, sums);
  bnapply_kernel<<<16384, 256, 0, stream>>>(x2f, t2, sums, bn3g, bn3b, (float*)d_out, nullptr);
}